// Round 1
// baseline (1369.984 us; speedup 1.0000x reference)
//
#include <hip/hip_runtime.h>

#define CIN 128
#define COUT 64

// ---------------------------------------------------------------------------
// Kernel 1: h = x @ W_root + b ; m = x @ W_nbr   (unchanged — proven)
// ---------------------------------------------------------------------------
__global__ __launch_bounds__(256) void gemm_hm_kernel(
        const float* __restrict__ x,
        const float* __restrict__ Wr,
        const float* __restrict__ Wn,
        const float* __restrict__ b,
        float* __restrict__ h,
        float* __restrict__ m,
        int n_coarse) {
    __shared__ float xs[32][CIN];
    const int rowBase = blockIdx.x * 32;

    if (rowBase + 32 <= n_coarse) {
        const float4* x4 = (const float4*)(x + (long long)rowBase * CIN);
        float4* xs4 = (float4*)&xs[0][0];
        for (int i = threadIdx.x; i < 32 * (CIN / 4); i += 256) xs4[i] = x4[i];
    } else {
        for (int i = threadIdx.x; i < 32 * CIN; i += 256) {
            int r = i / CIN, k = i % CIN;
            int row = rowBase + r;
            xs[r][k] = (row < n_coarse) ? x[(long long)row * CIN + k] : 0.f;
        }
    }
    __syncthreads();

    const int wv = threadIdx.x >> 6;
    const int c  = threadIdx.x & 63;
    const int r0 = wv * 8;

    float ah[8], am[8];
    const float bias = b[c];
#pragma unroll
    for (int j = 0; j < 8; ++j) { ah[j] = bias; am[j] = 0.f; }

    for (int k = 0; k < CIN; k += 4) {
        const float wr0 = Wr[(k + 0) * COUT + c];
        const float wr1 = Wr[(k + 1) * COUT + c];
        const float wr2 = Wr[(k + 2) * COUT + c];
        const float wr3 = Wr[(k + 3) * COUT + c];
        const float wn0 = Wn[(k + 0) * COUT + c];
        const float wn1 = Wn[(k + 1) * COUT + c];
        const float wn2 = Wn[(k + 2) * COUT + c];
        const float wn3 = Wn[(k + 3) * COUT + c];
#pragma unroll
        for (int j = 0; j < 8; ++j) {
            const float4 xv = *(const float4*)&xs[r0 + j][k];
            ah[j] = fmaf(xv.x, wr0, ah[j]);
            ah[j] = fmaf(xv.y, wr1, ah[j]);
            ah[j] = fmaf(xv.z, wr2, ah[j]);
            ah[j] = fmaf(xv.w, wr3, ah[j]);
            am[j] = fmaf(xv.x, wn0, am[j]);
            am[j] = fmaf(xv.y, wn1, am[j]);
            am[j] = fmaf(xv.z, wn2, am[j]);
            am[j] = fmaf(xv.w, wn3, am[j]);
        }
    }

#pragma unroll
    for (int j = 0; j < 8; ++j) {
        const int row = rowBase + r0 + j;
        if (row < n_coarse) {
            h[row * COUT + c] = ah[j];
            m[row * COUT + c] = am[j];
        }
    }
}

// ---------------------------------------------------------------------------
// CSR build, pass 1: histogram of destination degrees.
// ---------------------------------------------------------------------------
__global__ __launch_bounds__(256) void hist_kernel(
        const int* __restrict__ dst, int* __restrict__ cnt, int n) {
    const int e = blockIdx.x * 256 + threadIdx.x;
    if (e < n) atomicAdd(&cnt[dst[e]], 1);
}

// ---------------------------------------------------------------------------
// CSR build, pass 2: assign each row a contiguous slot range.
// Rows do NOT need monotonic bases — a per-block LDS scan plus one global
// cursor atomic per block replaces a device-wide prefix sum.
// ---------------------------------------------------------------------------
__global__ __launch_bounds__(256) void assign_base_kernel(
        const int* __restrict__ cnt, int* __restrict__ base,
        int* __restrict__ fill, int* __restrict__ cursor, int n) {
    __shared__ int s[256];
    __shared__ int blockBase;
    const int tid = threadIdx.x;
    const int i = blockIdx.x * 256 + tid;
    const int v = (i < n) ? cnt[i] : 0;
    s[tid] = v;
    __syncthreads();
#pragma unroll
    for (int off = 1; off < 256; off <<= 1) {
        int t = (tid >= off) ? s[tid - off] : 0;
        __syncthreads();
        if (tid >= off) s[tid] += t;
        __syncthreads();
    }
    if (tid == 255) blockBase = atomicAdd(cursor, s[255]);
    __syncthreads();
    if (i < n) {
        const int bse = blockBase + s[tid] - v;   // exclusive scan
        base[i] = bse;
        fill[i] = bse;
    }
}

// ---------------------------------------------------------------------------
// CSR build, pass 3: scatter edges into their row's slot range.
// Record = {src*COUT, weight_bits} : 8 B (half the old 16-B list entry).
// ---------------------------------------------------------------------------
__global__ __launch_bounds__(256) void scatter_kernel(
        const int* __restrict__ src, const int* __restrict__ dst,
        const float* __restrict__ w, int* __restrict__ fill,
        int2* __restrict__ edges, int n) {
    const int e = blockIdx.x * 256 + threadIdx.x;
    if (e >= n) return;
    const int d = dst[e];
    const int pos = atomicAdd(&fill[d], 1);
    edges[pos] = make_int2(src[e] * COUT, __float_as_int(w[e]));
}

// ---------------------------------------------------------------------------
// Gather over CSR: one wave per row, lane = channel. All loads are
// address-computable (no dependent chain); unroll-4 gives 8 outstanding
// loads per wave.
// ---------------------------------------------------------------------------
__global__ __launch_bounds__(256) void csr_gather_add_kernel(
        const float* __restrict__ m,
        const int* __restrict__ base, const int* __restrict__ cnt,
        const int2* __restrict__ edges,
        float* __restrict__ h, int n_rows) {
    const int row = blockIdx.x * 4 + (threadIdx.x >> 6);
    const int c = threadIdx.x & 63;
    if (row >= n_rows) return;
    const int p = base[row];
    const int n = cnt[row];
    float acc = 0.f;
    int j = 0;
    for (; j + 4 <= n; j += 4) {
        const int2 e0 = edges[p + j + 0];
        const int2 e1 = edges[p + j + 1];
        const int2 e2 = edges[p + j + 2];
        const int2 e3 = edges[p + j + 3];
        const float v0 = m[e0.x + c];
        const float v1 = m[e1.x + c];
        const float v2 = m[e2.x + c];
        const float v3 = m[e3.x + c];
        acc = fmaf(v0, __int_as_float(e0.y), acc);
        acc = fmaf(v1, __int_as_float(e1.y), acc);
        acc = fmaf(v2, __int_as_float(e2.y), acc);
        acc = fmaf(v3, __int_as_float(e3.y), acc);
    }
    for (; j < n; ++j) {
        const int2 e0 = edges[p + j];
        acc = fmaf(m[e0.x + c], __int_as_float(e0.y), acc);
    }
    h[row * COUT + c] += acc;
}

__global__ __launch_bounds__(256) void csr_gather_write_kernel(
        const float* __restrict__ h,
        const int* __restrict__ base, const int* __restrict__ cnt,
        const int2* __restrict__ edges,
        float* __restrict__ y, int n_rows) {
    const int row = blockIdx.x * 4 + (threadIdx.x >> 6);
    const int c = threadIdx.x & 63;
    if (row >= n_rows) return;
    const int p = base[row];
    const int n = cnt[row];
    float acc = 0.f;
    int j = 0;
    for (; j + 4 <= n; j += 4) {
        const int2 e0 = edges[p + j + 0];
        const int2 e1 = edges[p + j + 1];
        const int2 e2 = edges[p + j + 2];
        const int2 e3 = edges[p + j + 3];
        const float v0 = h[e0.x + c];
        const float v1 = h[e1.x + c];
        const float v2 = h[e2.x + c];
        const float v3 = h[e3.x + c];
        acc = fmaf(v0, __int_as_float(e0.y), acc);
        acc = fmaf(v1, __int_as_float(e1.y), acc);
        acc = fmaf(v2, __int_as_float(e2.y), acc);
        acc = fmaf(v3, __int_as_float(e3.y), acc);
    }
    for (; j < n; ++j) {
        const int2 e0 = edges[p + j];
        acc = fmaf(h[e0.x + c], __int_as_float(e0.y), acc);
    }
    y[row * COUT + c] = acc;   // full coverage -> no memset needed
}

extern "C" void kernel_launch(void* const* d_in, const int* in_sizes, int n_in,
                              void* d_out, int out_size, void* d_ws, size_t ws_size,
                              hipStream_t stream) {
    const float* x      = (const float*)d_in[0];
    const float* W_root = (const float*)d_in[1];
    const float* W_nbr  = (const float*)d_in[2];
    const float* b      = (const float*)d_in[3];
    const int*   eidx   = (const int*)d_in[4];   // [2, E]: row0=src, row1=dst
    const float* eattr  = (const float*)d_in[5];
    const int*   psrc   = (const int*)d_in[6];
    const int*   pdst   = (const int*)d_in[7];
    const float* pattr  = (const float*)d_in[8];

    const int n_coarse = in_sizes[0] / CIN;      // 200000
    const int n_edges  = in_sizes[4] / 2;        // 3200000
    const int n_pool   = in_sizes[6];            // 2400000
    const int n_fine   = out_size / COUT;        // 800000

    const int* esrc = eidx;
    const int* edst = eidx + n_edges;

    // ws layout (102.4 MB, unchanged footprint):
    float* h = (float*)d_ws;                       // [Nc, 64]  51.2 MB
    float* m = h + (size_t)n_coarse * COUT;        // [Nc, 64]  51.2 MB

    // Phase-1 CSR scratch lives in d_out (dead until the final kernel):
    //   edges1: n_edges * 8 B = 25.6 MB
    //   cnt1 / cursor1 / base1 / fill1: ~2.4 MB after it
    char* outb = (char*)d_out;
    int2* edges1  = (int2*)outb;
    char* p1      = outb + (size_t)n_edges * sizeof(int2);
    int*  cnt1    = (int*)p1;
    int*  cursor1 = (int*)(p1 + (size_t)n_coarse * 4);        // 16-B pad slot
    int*  base1   = (int*)(p1 + (size_t)n_coarse * 4 + 16);
    int*  fill1   = (int*)(p1 + (size_t)n_coarse * 4 + 16 + (size_t)n_coarse * 4);

    // Phase-2 CSR scratch overlays m (dead after edge gather):
    //   edges2: n_pool * 8 B = 19.2 MB, cnt2/cursor2/base2/fill2: ~9.6 MB
    char* mb      = (char*)m;
    int2* edges2  = (int2*)mb;
    char* p2      = mb + (size_t)n_pool * sizeof(int2);
    int*  cnt2    = (int*)p2;
    int*  cursor2 = (int*)(p2 + (size_t)n_fine * 4);
    int*  base2   = (int*)(p2 + (size_t)n_fine * 4 + 16);
    int*  fill2   = (int*)(p2 + (size_t)n_fine * 4 + 16 + (size_t)n_fine * 4);

    // 1) dense transforms: h = x@Wr + b, m = x@Wn
    gemm_hm_kernel<<<(n_coarse + 31) / 32, 256, 0, stream>>>(x, W_root, W_nbr, b, h, m, n_coarse);

    // 2) phase-1 CSR build (scratch in d_out)
    hipMemsetAsync(cnt1, 0, (size_t)n_coarse * 4 + 16, stream);   // cnt1 + cursor1
    hist_kernel<<<(n_edges + 255) / 256, 256, 0, stream>>>(edst, cnt1, n_edges);
    assign_base_kernel<<<(n_coarse + 255) / 256, 256, 0, stream>>>(cnt1, base1, fill1, cursor1, n_coarse);
    scatter_kernel<<<(n_edges + 255) / 256, 256, 0, stream>>>(esrc, edst, eattr, fill1, edges1, n_edges);

    // 3) edge aggregation: h += sum over in-edges of m[src]*w
    csr_gather_add_kernel<<<(n_coarse + 3) / 4, 256, 0, stream>>>(
        m, base1, cnt1, edges1, h, n_coarse);

    // 4) phase-2 CSR build (m buffer is now dead; reuse it)
    hipMemsetAsync(cnt2, 0, (size_t)n_fine * 4 + 16, stream);     // cnt2 + cursor2
    hist_kernel<<<(n_pool + 255) / 256, 256, 0, stream>>>(pdst, cnt2, n_pool);
    assign_base_kernel<<<(n_fine + 255) / 256, 256, 0, stream>>>(cnt2, base2, fill2, cursor2, n_fine);
    scatter_kernel<<<(n_pool + 255) / 256, 256, 0, stream>>>(psrc, pdst, pattr, fill2, edges2, n_pool);

    // 5) unpool gather: every output row written exactly once
    csr_gather_write_kernel<<<(n_fine + 3) / 4, 256, 0, stream>>>(
        h, base2, cnt2, edges2, (float*)d_out, n_fine);
}

// Round 2
// 1297.319 us; speedup vs baseline: 1.0560x; 1.0560x over previous
//
#include <hip/hip_runtime.h>

#define CIN 128
#define COUT 64
#define NXCD 8

// ---------------------------------------------------------------------------
// Kernel 1: h = x @ W_root + b ; m = x @ W_nbr   (unchanged — proven)
// ---------------------------------------------------------------------------
__global__ __launch_bounds__(256) void gemm_hm_kernel(
        const float* __restrict__ x,
        const float* __restrict__ Wr,
        const float* __restrict__ Wn,
        const float* __restrict__ b,
        float* __restrict__ h,
        float* __restrict__ m,
        int n_coarse) {
    __shared__ float xs[32][CIN];
    const int rowBase = blockIdx.x * 32;

    if (rowBase + 32 <= n_coarse) {
        const float4* x4 = (const float4*)(x + (long long)rowBase * CIN);
        float4* xs4 = (float4*)&xs[0][0];
        for (int i = threadIdx.x; i < 32 * (CIN / 4); i += 256) xs4[i] = x4[i];
    } else {
        for (int i = threadIdx.x; i < 32 * CIN; i += 256) {
            int r = i / CIN, k = i % CIN;
            int row = rowBase + r;
            xs[r][k] = (row < n_coarse) ? x[(long long)row * CIN + k] : 0.f;
        }
    }
    __syncthreads();

    const int wv = threadIdx.x >> 6;
    const int c  = threadIdx.x & 63;
    const int r0 = wv * 8;

    float ah[8], am[8];
    const float bias = b[c];
#pragma unroll
    for (int j = 0; j < 8; ++j) { ah[j] = bias; am[j] = 0.f; }

    for (int k = 0; k < CIN; k += 4) {
        const float wr0 = Wr[(k + 0) * COUT + c];
        const float wr1 = Wr[(k + 1) * COUT + c];
        const float wr2 = Wr[(k + 2) * COUT + c];
        const float wr3 = Wr[(k + 3) * COUT + c];
        const float wn0 = Wn[(k + 0) * COUT + c];
        const float wn1 = Wn[(k + 1) * COUT + c];
        const float wn2 = Wn[(k + 2) * COUT + c];
        const float wn3 = Wn[(k + 3) * COUT + c];
#pragma unroll
        for (int j = 0; j < 8; ++j) {
            const float4 xv = *(const float4*)&xs[r0 + j][k];
            ah[j] = fmaf(xv.x, wr0, ah[j]);
            ah[j] = fmaf(xv.y, wr1, ah[j]);
            ah[j] = fmaf(xv.z, wr2, ah[j]);
            ah[j] = fmaf(xv.w, wr3, ah[j]);
            am[j] = fmaf(xv.x, wn0, am[j]);
            am[j] = fmaf(xv.y, wn1, am[j]);
            am[j] = fmaf(xv.z, wn2, am[j]);
            am[j] = fmaf(xv.w, wn3, am[j]);
        }
    }

#pragma unroll
    for (int j = 0; j < 8; ++j) {
        const int row = rowBase + r0 + j;
        if (row < n_coarse) {
            h[row * COUT + c] = ah[j];
            m[row * COUT + c] = am[j];
        }
    }
}

// ---------------------------------------------------------------------------
// CSR build, pass 1 (XCD-partitioned): histogram of destination degrees.
// Blocks with (blockIdx & 7) == r handle only dst rows in range r, so each
// cnt[] line is touched by a single XCD and stays resident in its L2.
// ---------------------------------------------------------------------------
__global__ __launch_bounds__(256) void hist_xcd_kernel(
        const int* __restrict__ dst, int* __restrict__ cnt, int n, int rpr) {
    const int range = blockIdx.x & (NXCD - 1);
    const int lo = range * rpr;
    const int hi = lo + rpr;
    const int tpr = (gridDim.x >> 3) * 256;           // threads per range
    const int ng = (n + 3) >> 2;                      // groups of 4 edges
    const int4* __restrict__ dst4 = (const int4*)dst;
    for (int g = (blockIdx.x >> 3) * 256 + threadIdx.x; g < ng; g += tpr) {
        const int e0 = g << 2;
        if (e0 + 3 < n) {
            const int4 d4 = dst4[g];
            if (d4.x >= lo && d4.x < hi) atomicAdd(&cnt[d4.x], 1);
            if (d4.y >= lo && d4.y < hi) atomicAdd(&cnt[d4.y], 1);
            if (d4.z >= lo && d4.z < hi) atomicAdd(&cnt[d4.z], 1);
            if (d4.w >= lo && d4.w < hi) atomicAdd(&cnt[d4.w], 1);
        } else {
            for (int k = 0; k < 4 && e0 + k < n; ++k) {
                const int d = dst[e0 + k];
                if (d >= lo && d < hi) atomicAdd(&cnt[d], 1);
            }
        }
    }
}

// ---------------------------------------------------------------------------
// CSR build, pass 2: assign each row a contiguous slot range (block scan +
// one global cursor atomic; bases need not be monotonic across rows).
// ---------------------------------------------------------------------------
__global__ __launch_bounds__(256) void assign_base_kernel(
        const int* __restrict__ cnt, int* __restrict__ base,
        int* __restrict__ fill, int* __restrict__ cursor, int n) {
    __shared__ int s[256];
    __shared__ int blockBase;
    const int tid = threadIdx.x;
    const int i = blockIdx.x * 256 + tid;
    const int v = (i < n) ? cnt[i] : 0;
    s[tid] = v;
    __syncthreads();
#pragma unroll
    for (int off = 1; off < 256; off <<= 1) {
        int t = (tid >= off) ? s[tid - off] : 0;
        __syncthreads();
        if (tid >= off) s[tid] += t;
        __syncthreads();
    }
    if (tid == 255) blockBase = atomicAdd(cursor, s[255]);
    __syncthreads();
    if (i < n) {
        const int bse = blockBase + s[tid] - v;   // exclusive scan
        base[i] = bse;
        fill[i] = bse;
    }
}

// ---------------------------------------------------------------------------
// CSR build, pass 3 (XCD-partitioned scatter). Each range's edge slots and
// fill[] cursors live in one XCD's L2 -> full-line write combining, local
// atomics. Record = {src*COUT, weight_bits} : 8 B.
// ---------------------------------------------------------------------------
__global__ __launch_bounds__(256) void scatter_xcd_kernel(
        const int* __restrict__ src, const int* __restrict__ dst,
        const float* __restrict__ w, int* __restrict__ fill,
        int2* __restrict__ edges, int n, int rpr) {
    const int range = blockIdx.x & (NXCD - 1);
    const int lo = range * rpr;
    const int hi = lo + rpr;
    const int tpr = (gridDim.x >> 3) * 256;
    const int ng = (n + 3) >> 2;
    const int4* __restrict__ dst4 = (const int4*)dst;
    for (int g = (blockIdx.x >> 3) * 256 + threadIdx.x; g < ng; g += tpr) {
        const int e0 = g << 2;
        if (e0 + 3 < n) {
            const int4 d4 = dst4[g];
            const int dd[4] = {d4.x, d4.y, d4.z, d4.w};
#pragma unroll
            for (int k = 0; k < 4; ++k) {
                const int d = dd[k];
                if (d >= lo && d < hi) {
                    const int pos = atomicAdd(&fill[d], 1);
                    edges[pos] = make_int2(src[e0 + k] * COUT,
                                           __float_as_int(w[e0 + k]));
                }
            }
        } else {
            for (int k = 0; k < 4 && e0 + k < n; ++k) {
                const int d = dst[e0 + k];
                if (d >= lo && d < hi) {
                    const int pos = atomicAdd(&fill[d], 1);
                    edges[pos] = make_int2(src[e0 + k] * COUT,
                                           __float_as_int(w[e0 + k]));
                }
            }
        }
    }
}

// ---------------------------------------------------------------------------
// Gather over CSR: one wave per row, lane = channel. All loads are
// address-computable; unroll-4 gives 8 outstanding loads per wave.
// ---------------------------------------------------------------------------
__global__ __launch_bounds__(256) void csr_gather_add_kernel(
        const float* __restrict__ m,
        const int* __restrict__ base, const int* __restrict__ cnt,
        const int2* __restrict__ edges,
        float* __restrict__ h, int n_rows) {
    const int row = blockIdx.x * 4 + (threadIdx.x >> 6);
    const int c = threadIdx.x & 63;
    if (row >= n_rows) return;
    const int p = base[row];
    const int n = cnt[row];
    float acc = 0.f;
    int j = 0;
    for (; j + 4 <= n; j += 4) {
        const int2 e0 = edges[p + j + 0];
        const int2 e1 = edges[p + j + 1];
        const int2 e2 = edges[p + j + 2];
        const int2 e3 = edges[p + j + 3];
        const float v0 = m[e0.x + c];
        const float v1 = m[e1.x + c];
        const float v2 = m[e2.x + c];
        const float v3 = m[e3.x + c];
        acc = fmaf(v0, __int_as_float(e0.y), acc);
        acc = fmaf(v1, __int_as_float(e1.y), acc);
        acc = fmaf(v2, __int_as_float(e2.y), acc);
        acc = fmaf(v3, __int_as_float(e3.y), acc);
    }
    for (; j < n; ++j) {
        const int2 e0 = edges[p + j];
        acc = fmaf(m[e0.x + c], __int_as_float(e0.y), acc);
    }
    h[row * COUT + c] += acc;
}

__global__ __launch_bounds__(256) void csr_gather_write_kernel(
        const float* __restrict__ h,
        const int* __restrict__ base, const int* __restrict__ cnt,
        const int2* __restrict__ edges,
        float* __restrict__ y, int n_rows) {
    const int row = blockIdx.x * 4 + (threadIdx.x >> 6);
    const int c = threadIdx.x & 63;
    if (row >= n_rows) return;
    const int p = base[row];
    const int n = cnt[row];
    float acc = 0.f;
    int j = 0;
    for (; j + 4 <= n; j += 4) {
        const int2 e0 = edges[p + j + 0];
        const int2 e1 = edges[p + j + 1];
        const int2 e2 = edges[p + j + 2];
        const int2 e3 = edges[p + j + 3];
        const float v0 = h[e0.x + c];
        const float v1 = h[e1.x + c];
        const float v2 = h[e2.x + c];
        const float v3 = h[e3.x + c];
        acc = fmaf(v0, __int_as_float(e0.y), acc);
        acc = fmaf(v1, __int_as_float(e1.y), acc);
        acc = fmaf(v2, __int_as_float(e2.y), acc);
        acc = fmaf(v3, __int_as_float(e3.y), acc);
    }
    for (; j < n; ++j) {
        const int2 e0 = edges[p + j];
        acc = fmaf(h[e0.x + c], __int_as_float(e0.y), acc);
    }
    y[row * COUT + c] = acc;   // full coverage -> no memset needed
}

extern "C" void kernel_launch(void* const* d_in, const int* in_sizes, int n_in,
                              void* d_out, int out_size, void* d_ws, size_t ws_size,
                              hipStream_t stream) {
    const float* x      = (const float*)d_in[0];
    const float* W_root = (const float*)d_in[1];
    const float* W_nbr  = (const float*)d_in[2];
    const float* b      = (const float*)d_in[3];
    const int*   eidx   = (const int*)d_in[4];   // [2, E]: row0=src, row1=dst
    const float* eattr  = (const float*)d_in[5];
    const int*   psrc   = (const int*)d_in[6];
    const int*   pdst   = (const int*)d_in[7];
    const float* pattr  = (const float*)d_in[8];

    const int n_coarse = in_sizes[0] / CIN;      // 200000
    const int n_edges  = in_sizes[4] / 2;        // 3200000
    const int n_pool   = in_sizes[6];            // 2400000
    const int n_fine   = out_size / COUT;        // 800000

    const int* esrc = eidx;
    const int* edst = eidx + n_edges;

    // ws layout (102.4 MB, unchanged footprint):
    float* h = (float*)d_ws;                       // [Nc, 64]  51.2 MB
    float* m = h + (size_t)n_coarse * COUT;        // [Nc, 64]  51.2 MB

    // Phase-1 CSR scratch lives in d_out (dead until the final kernel):
    char* outb = (char*)d_out;
    int2* edges1  = (int2*)outb;
    char* p1      = outb + (size_t)n_edges * sizeof(int2);
    int*  cnt1    = (int*)p1;
    int*  cursor1 = (int*)(p1 + (size_t)n_coarse * 4);
    int*  base1   = (int*)(p1 + (size_t)n_coarse * 4 + 16);
    int*  fill1   = (int*)(p1 + (size_t)n_coarse * 4 + 16 + (size_t)n_coarse * 4);

    // Phase-2 CSR scratch overlays m (dead after edge gather):
    char* mb      = (char*)m;
    int2* edges2  = (int2*)mb;
    char* p2      = mb + (size_t)n_pool * sizeof(int2);
    int*  cnt2    = (int*)p2;
    int*  cursor2 = (int*)(p2 + (size_t)n_fine * 4);
    int*  base2   = (int*)(p2 + (size_t)n_fine * 4 + 16);
    int*  fill2   = (int*)(p2 + (size_t)n_fine * 4 + 16 + (size_t)n_fine * 4);

    const int rpr1 = (n_coarse + NXCD - 1) / NXCD;   // rows per XCD range
    const int rpr2 = (n_fine + NXCD - 1) / NXCD;

    // 1) dense transforms: h = x@Wr + b, m = x@Wn
    gemm_hm_kernel<<<(n_coarse + 31) / 32, 256, 0, stream>>>(x, W_root, W_nbr, b, h, m, n_coarse);

    // 2) phase-1 CSR build (scratch in d_out)
    hipMemsetAsync(cnt1, 0, (size_t)n_coarse * 4 + 16, stream);   // cnt1 + cursor1
    hist_xcd_kernel<<<2048, 256, 0, stream>>>(edst, cnt1, n_edges, rpr1);
    assign_base_kernel<<<(n_coarse + 255) / 256, 256, 0, stream>>>(cnt1, base1, fill1, cursor1, n_coarse);
    scatter_xcd_kernel<<<2048, 256, 0, stream>>>(esrc, edst, eattr, fill1, edges1, n_edges, rpr1);

    // 3) edge aggregation: h += sum over in-edges of m[src]*w
    csr_gather_add_kernel<<<(n_coarse + 3) / 4, 256, 0, stream>>>(
        m, base1, cnt1, edges1, h, n_coarse);

    // 4) phase-2 CSR build (m buffer is now dead; reuse it)
    hipMemsetAsync(cnt2, 0, (size_t)n_fine * 4 + 16, stream);     // cnt2 + cursor2
    hist_xcd_kernel<<<2048, 256, 0, stream>>>(pdst, cnt2, n_pool, rpr2);
    assign_base_kernel<<<(n_fine + 255) / 256, 256, 0, stream>>>(cnt2, base2, fill2, cursor2, n_fine);
    scatter_xcd_kernel<<<2048, 256, 0, stream>>>(psrc, pdst, pattr, fill2, edges2, n_pool, rpr2);

    // 5) unpool gather: every output row written exactly once
    csr_gather_write_kernel<<<(n_fine + 3) / 4, 256, 0, stream>>>(
        h, base2, cnt2, edges2, (float*)d_out, n_fine);
}